// Round 4
// baseline (817.337 us; speedup 1.0000x reference)
//
#include <hip/hip_runtime.h>
#include <hip/hip_bf16.h>
#include <math.h>

#define L_SZ 1024
#define STRIDE_ 32
#define WIN 8
#define PNUM 31
#define NPATCH 31744   // 1024 batches x 31 patches
#define SGRID 768      // 256 CU x 3 blocks/CU, all co-resident

// LDS row strides (in shorts). dword strides = 36/68 = 4 mod 32 -> 2-way banks (free).
#define X1TS 72
#define CAS  136

typedef __attribute__((ext_vector_type(8))) short short8;
typedef __attribute__((ext_vector_type(4))) short short4v;
typedef __attribute__((ext_vector_type(4))) float f32x4;

#define MFMA16(a, b, c) __builtin_amdgcn_mfma_f32_16x16x32_bf16(a, b, c, 0, 0, 0)

__device__ __forceinline__ float sigf(float x) { return 1.0f / (1.0f + __expf(-x)); }
__device__ __forceinline__ float tanhfast(float x) {
    float ax = fabsf(x);
    float t = __expf(-2.0f * ax);
    return copysignf((1.0f - t) / (1.0f + t), x);
}
__device__ __forceinline__ short f2bf(float f) {
    __hip_bfloat16 h = __float2bfloat16(f);   // RNE
    return *reinterpret_cast<short*>(&h);
}
__device__ __forceinline__ float bf2f(short s) {
    __hip_bfloat16 h = *reinterpret_cast<__hip_bfloat16*>(&s);
    return __bfloat162float(h);
}
__device__ __forceinline__ float f4c(float4 v, int k) {
    return k == 0 ? v.x : (k == 1 ? v.y : (k == 2 ? v.z : v.w));
}
__device__ __forceinline__ void fma4(float4& acc, float s, float4 v) {
    acc.x += s * v.x; acc.y += s * v.y; acc.z += s * v.z; acc.w += s * v.w;
}

// ---------------------------------------------------------------------------
// adjn[i][j] = sigmoid(ew[i][j]) * mask(|i-j|<=8, i!=j) * deg_inv[i]
// ---------------------------------------------------------------------------
__global__ void adj_kernel(const float* __restrict__ ew, float* __restrict__ adjn) {
    int i = threadIdx.x;
    if (i >= 64) return;
    float sum = 0.f;
    for (int j = 0; j < 64; ++j) {
        int d = i - j; d = d < 0 ? -d : d;
        float a = (d <= WIN && d != 0) ? sigf(ew[i * 64 + j]) : 0.f;
        sum += a;
    }
    float dinv = (sum > 0.f) ? 1.0f / sum : 0.f;
    for (int j = 0; j < 64; ++j) {
        int d = i - j; d = d < 0 ? -d : d;
        float a = (d <= WIN && d != 0) ? sigf(ew[i * 64 + j]) : 0.f;
        adjn[i * 64 + j] = a * dinv;
    }
}

// ---------------------------------------------------------------------------
// prep (unchanged from R15):
//   blocks   0..127 : Wih0T | 128..383 : Wih1T | 384..393 : sage frags
//   blocks 394..457 : Whh0 frags hi/lo | 458..521 : Whh1 frags hi/lo
// ---------------------------------------------------------------------------
__global__ void prep_kernel(const float* __restrict__ Wih0, const float* __restrict__ Whh0,
                            const float* __restrict__ Wih1, const float* __restrict__ Whh1,
                            const float* __restrict__ adjn,
                            const float* __restrict__ Ws2, const float* __restrict__ Wn2,
                            float* __restrict__ Wih0T, float* __restrict__ Wih1T,
                            short* __restrict__ adjfG, short* __restrict__ wcatfG,
                            short* __restrict__ whhf0G, short* __restrict__ whhf1G) {
    int bid = blockIdx.x, tid = threadIdx.x;
    if (bid < 128) {
        int e = bid * 256 + tid;
        int k = e >> 9, j = e & 511;
        Wih0T[e] = Wih0[j * 64 + k];
        return;
    }
    if (bid < 384) {
        int e = (bid - 128) * 256 + tid;
        int k = e >> 9, j = e & 511;
        Wih1T[e] = Wih1[j * 128 + k];
        return;
    }
    if (bid < 394) {
        int t = (bid - 384) * 256 + tid;
        if (t >= 2432) return;
        int f = t >> 6, l = t & 63;
        int q = l >> 4, l15 = l & 15;
        short8 v;
        if (f < 6) {
            const int ntT[6] = {0, 1, 1, 2, 2, 3};
            const int ksT[6] = {0, 0, 1, 0, 1, 1};
            int row = l15 + 16 * ntT[f], col = 8 * q + 32 * ksT[f];
            #pragma unroll
            for (int e = 0; e < 8; ++e)
                v[e] = f2bf(adjn[row * 64 + col + e]);
            *(short8*)(adjfG + ((size_t)f * 64 + l) * 8) = v;
        } else {
            int fi = f - 6;
            int isLo = fi >= 16;
            int ff = isLo ? fi - 16 : fi;
            int nt = ff >> 2, ks = ff & 3;
            int oo = l15 + 16 * nt;
            #pragma unroll
            for (int e = 0; e < 8; ++e) {
                int k = 32 * ks + 8 * q + e;
                float src = (k < 64) ? Ws2[oo * 64 + k] : Wn2[oo * 64 + (k - 64)];
                short hi = f2bf(src);
                v[e] = isLo ? f2bf(src - bf2f(hi)) : hi;
            }
            *(short8*)(wcatfG + ((size_t)fi * 64 + l) * 8) = v;
        }
        return;
    }
    {
        int layer = (bid < 458) ? 0 : 1;
        int base = layer ? 458 : 394;
        const float* Whh = layer ? Whh1 : Whh0;
        short* dst = layer ? whhf1G : whhf0G;
        int t = (bid - base) * 256 + tid;    // 0..16383
        int frag = t >> 6, l = t & 63;
        int hl = frag & 1, ks = (frag >> 1) & 3, NT = frag >> 3;
        int g = NT * 16 + (l & 15);
        int kbase = ks * 32 + (l >> 4) * 8;
        short8 v;
        #pragma unroll
        for (int e = 0; e < 8; ++e) {
            float src = Whh[(size_t)g * 128 + kbase + e];
            short hi = f2bf(src);
            v[e] = hl ? f2bf(src - bf2f(hi)) : hi;
        }
        *(short8*)(dst + (size_t)t * 8) = v;
    }
}

// ---------------------------------------------------------------------------
// Persistent fused SAGE, bf16 MFMA.
// R19: shorten the per-iteration serial chain (R18: 12.8k cyc wall vs ~4k
// issued; VALU 34 / MFMA 15 / occ 34 -> latency-bound).
//  (1) adjn band -> 17 registers, hoisted out of the patch loop (lane i only
//      needs adjn[i][i-8..i+8]; patch-invariant).
//  (2) n0 via __shfl from lane-resident x0: fixed-trip d=-8..8, fully
//      unrolled. Out-of-band terms multiply the EXACT 0.0f band weights ->
//      sum bit-identical; in-band terms keep ascending-j order. Deletes the
//      s_x0 stage phase and its barrier.
//  (3) next-patch x0 prefetched into registers at iteration top (hidden
//      under phase1 + MFMA).
//  (4) s_x1T/s_cat double-buffered (53,248 B; 3 blocks/CU = 159,744 <=
//      163,840) -> 2 barriers/iter; WAR across iters ruled out by the two
//      collective barriers.
// Reg budget ~115 < 170 licensed by (256,3) -> no spill (watch FETCH_SIZE).
// ---------------------------------------------------------------------------
__launch_bounds__(256, 3)
__global__ void sage_mfma(const float* __restrict__ I, const float* __restrict__ Q,
                          const float* __restrict__ adjn,
                          const float* __restrict__ Wn1, const float* __restrict__ bn1,
                          const float* __restrict__ Ws1, const float* __restrict__ bs1,
                          const float* __restrict__ bn2, const float* __restrict__ bs2,
                          const short* __restrict__ adjfG, const short* __restrict__ wcatfG,
                          float* __restrict__ feats) {
    __shared__ __align__(16) short s_x1T[2][64 * X1TS];  // x1^T [o][i] bf16
    __shared__ __align__(16) short s_cat[2][64 * CAS];   // [i][x1|n1] bf16

    const int tid = threadIdx.x;
    const int w = tid >> 6, l = tid & 63, q = l >> 4, l15 = l & 15;

    // adj frags for THIS wave's i-tile (band): w0:{ks0}, w1/w2:{ks0,ks1}, w3:{ks1}
    const bool hasKs0 = (w <= 2);
    const bool hasKs1 = (w >= 1);
    const int idx0 = (w == 0) ? 0 : (w == 1 ? 1 : 3);    // frag idx for (nt=w, ks=0)
    const int idx1 = (w == 1) ? 2 : (w == 2 ? 4 : 5);    // frag idx for (nt=w, ks=1)
    short8 adjB0 = {}, adjB1 = {};
    if (hasKs0) adjB0 = *(const short8*)(adjfG + ((size_t)idx0 * 64 + l) * 8);
    if (hasKs1) adjB1 = *(const short8*)(adjfG + ((size_t)idx1 * 64 + l) * 8);

    // weight frags for THIS wave's o-tile (nt = w): 8 frags = 32 VGPRs
    short8 whf[4], wlf[4];
    #pragma unroll
    for (int ks = 0; ks < 4; ++ks) {
        whf[ks] = *(const short8*)(wcatfG + ((size_t)(w * 4 + ks) * 64 + l) * 8);
        wlf[ks] = *(const short8*)(wcatfG + ((size_t)(w * 4 + ks + 16) * 64 + l) * 8);
    }
    // bias for this wave's output channel (loop-invariant)
    const int oo = l15 + 16 * w;
    const float bo = bs2[oo] + bn2[oo];

    // (1) adjn band in registers: lane l = row i; zeros outside [0,64)
    float areg[17];
    #pragma unroll
    for (int d = 0; d < 17; ++d) {
        int j = l + d - WIN;
        areg[d] = (j >= 0 && j < 64) ? adjn[l * 64 + j] : 0.f;
    }

    // initial x0 (lane l holds column i = l; same in all 4 waves, L1-broadcast)
    int m = blockIdx.x;
    float x0a, x0b;
    {
        int b = m / PNUM, p = m % PNUM;
        x0a = I[(size_t)b * L_SZ + p * STRIDE_ + l];
        x0b = Q[(size_t)b * L_SZ + p * STRIDE_ + l];
    }

    int pb = 0;
    while (m < NPATCH) {
        // (3) prefetch next patch's x0 — independent, hides global latency
        const int mn = m + SGRID;
        float nxa = 0.f, nxb = 0.f;
        if (mn < NPATCH) {
            int bn = mn / PNUM, pn = mn % PNUM;
            nxa = I[(size_t)bn * L_SZ + pn * STRIDE_ + l];
            nxb = Q[(size_t)bn * L_SZ + pn * STRIDE_ + l];
        }

        short* __restrict__ x1T = s_x1T[pb];
        short* __restrict__ cat = s_cat[pb];

        // ---- Phase 1: n0 via shuffles, x1 = relu(...) ----
        {
            // (2) fixed-trip window; out-of-band areg == 0.0f exactly
            float n0a = 0.f, n0b = 0.f;
            #pragma unroll
            for (int d = 0; d < 17; ++d) {
                int j = l + d - WIN;
                float xa = __shfl(x0a, j, 64);
                float xb = __shfl(x0b, j, 64);
                n0a += areg[d] * xa;
                n0b += areg[d] * xb;
            }
            union { short s[16]; short8 v[2]; } pk;
            #pragma unroll
            for (int t = 0; t < 16; ++t) {
                int o = w * 16 + t;
                float2 wsv = ((const float2*)Ws1)[o];
                float2 wnv = ((const float2*)Wn1)[o];
                float v = bs1[o] + bn1[o] + wsv.x * x0a + wsv.y * x0b
                                          + wnv.x * n0a + wnv.y * n0b;
                v = fmaxf(v, 0.f);
                short bv = f2bf(v);
                x1T[o * X1TS + l] = bv;
                pk.s[t] = bv;
            }
            *(short8*)&cat[l * CAS + w * 16]     = pk.v[0];
            *(short8*)&cat[l * CAS + w * 16 + 8] = pk.v[1];
        }
        __syncthreads();   // barrier 1: x1T/cat(x1) visible to all waves

        // ---- MFMA#1: n1^T for i-tile w. A = x1T o-tiles, B = adj cols. ----
        #pragma unroll
        for (int ot = 0; ot < 4; ++ot) {
            f32x4 c = {0.f, 0.f, 0.f, 0.f};
            if (hasKs0) {
                short8 a = *(const short8*)&x1T[(16 * ot + l15) * X1TS + 8 * q];
                c = MFMA16(a, adjB0, c);
            }
            if (hasKs1) {
                short8 a = *(const short8*)&x1T[(16 * ot + l15) * X1TS + 8 * q + 32];
                c = MFMA16(a, adjB1, c);
            }
            // C: col i = 16w+l15 (lane), rows o = 16ot+4q+reg -> b64 write
            short4v nv;
            nv[0] = f2bf(c[0]); nv[1] = f2bf(c[1]);
            nv[2] = f2bf(c[2]); nv[3] = f2bf(c[3]);
            *(short4v*)&cat[(16 * w + l15) * CAS + 64 + 16 * ot + 4 * q] = nv;
        }
        __syncthreads();   // barrier 2: n1 consumed cross-wave

        // ---- MFMA#2: wave w owns o-tile nt=w; loop all 4 i-tiles ----
        {
            f32x4 z = {0.f, 0.f, 0.f, 0.f};
            f32x4 acc2[4] = {z, z, z, z};
            #pragma unroll
            for (int it2 = 0; it2 < 4; ++it2) {
                short8 a2[4];
                #pragma unroll
                for (int ks = 0; ks < 4; ++ks)
                    a2[ks] = *(const short8*)&cat[(16 * it2 + l15) * CAS + 32 * ks + 8 * q];
                #pragma unroll
                for (int ks = 0; ks < 4; ++ks) {
                    acc2[it2] = MFMA16(a2[ks], whf[ks], acc2[it2]);
                    acc2[it2] = MFMA16(a2[ks], wlf[ks], acc2[it2]);
                }
            }
            float total = 0.f;
            #pragma unroll
            for (int it2 = 0; it2 < 4; ++it2) {
                float s = fmaxf(acc2[it2][0] + bo, 0.f) + fmaxf(acc2[it2][1] + bo, 0.f)
                        + fmaxf(acc2[it2][2] + bo, 0.f) + fmaxf(acc2[it2][3] + bo, 0.f);
                s += __shfl_xor(s, 16);
                s += __shfl_xor(s, 32);
                total += s;           // ((s0+s1)+s2)+s3 — same order as before
            }
            if (l < 16)
                feats[(size_t)m * 64 + 16 * w + l15] = total;
        }
        // no trailing barrier: next iter writes buffer pb^1; the two collective
        // barriers per iter prevent any wave from lapping into this buffer.
        x0a = nxa; x0b = nxb; m = mn; pb ^= 1;
    }
}

// ---------------------------------------------------------------------------
// GEMM: C[M x 512] = A[M x K] @ BT[K x 512] + bias1 + bias2  (verified)
// ---------------------------------------------------------------------------
template <int K>
__launch_bounds__(256, 2)
__global__ void gemm512_kernel(const float* __restrict__ A, const float* __restrict__ BT,
                               const float* __restrict__ bias1, const float* __restrict__ bias2,
                               float* __restrict__ C) {
    constexpr int K4 = K / 4;
    __shared__ __align__(16) float s_a[64 * K];
    const int tid = threadIdx.x;
    const int m0 = blockIdx.x * 64;
    const int j0 = blockIdx.y * 128;

    const float4* Ag = (const float4*)A;
    for (int e = tid; e < 16 * K; e += 256) {
        int row = e / K4, c = e % K4;
        ((float4*)s_a)[row * K4 + (c ^ ((row >> 2) & 7))] = Ag[(size_t)(m0 + row) * K4 + c];
    }
    __syncthreads();

    const int ti = tid >> 4, tj = tid & 15;
    const int swz = ti & 7;
    const int j = j0 + tj * 8;
    const int jb = (j0 >> 2) + tj * 2;
    const float4* BT4 = (const float4*)BT;

    float4 accL[4], accH[4];
    #pragma unroll
    for (int ii = 0; ii < 4; ++ii) {
        accL[ii] = make_float4(0.f, 0.f, 0.f, 0.f);
        accH[ii] = make_float4(0.f, 0.f, 0.f, 0.f);
    }
    for (int c = 0; c < K4; ++c) {
        float4 a4[4];
        #pragma unroll
        for (int ii = 0; ii < 4; ++ii)
            a4[ii] = ((const float4*)s_a)[(4 * ti + ii) * K4 + (c ^ swz)];
        #pragma unroll
        for (int kk = 0; kk < 4; ++kk) {
            float4 b1 = BT4[(size_t)(c * 4 + kk) * 128 + jb];
            float4 b2 = BT4[(size_t)(c * 4 + kk) * 128 + jb + 1];
            #pragma unroll
            for (int ii = 0; ii < 4; ++ii) {
                float av = f4c(a4[ii], kk);
                fma4(accL[ii], av, b1);
                fma4(accH[ii], av, b2);
            }
        }
    }
    float4 bL = make_float4(bias1[j] + bias2[j], bias1[j + 1] + bias2[j + 1],
                            bias1[j + 2] + bias2[j + 2], bias1[j + 3] + bias2[j + 3]);
    float4 bH = make_float4(bias1[j + 4] + bias2[j + 4], bias1[j + 5] + bias2[j + 5],
                            bias1[j + 6] + bias2[j + 6], bias1[j + 7] + bias2[j + 7]);
    #pragma unroll
    for (int ii = 0; ii < 4; ++ii) {
        size_t row = (size_t)(m0 + 4 * ti + ii);
        float4 oL = make_float4(accL[ii].x + bL.x, accL[ii].y + bL.y,
                                accL[ii].z + bL.z, accL[ii].w + bL.w);
        float4 oH = make_float4(accH[ii].x + bH.x, accH[ii].y + bH.y,
                                accH[ii].z + bH.z, accH[ii].w + bH.w);
        ((float4*)C)[(row * 512 + j) >> 2] = oL;
        ((float4*)C)[(row * 512 + j + 4) >> 2] = oH;
    }
}

// ---------------------------------------------------------------------------
// LSTM recurrence v4: MFMA (unchanged from R14/R15).
// ---------------------------------------------------------------------------
#define HS 136    // s_h row stride in shorts (68 dwords = 4 mod 32)
#define GS 516    // s_g2 row stride in floats (516 = 4 mod 32, 16B-mult)

template <bool FINAL>
__launch_bounds__(512)
__global__ void lstm_mfma(const float* __restrict__ xg, const short* __restrict__ whhfG,
                          float* __restrict__ out0,
                          const float* __restrict__ Wc1, const float* __restrict__ bc1,
                          const float* __restrict__ Wc2, const float* __restrict__ bc2,
                          float* __restrict__ out) {
    __shared__ __align__(16) short s_h[16 * HS];    // h bf16 [m][k]
    __shared__ __align__(16) float s_g2[16 * GS];   // mfma gates fp32 [m][n]
    __shared__ __align__(16) float s_hid[16 * 68];
    const int tid = threadIdx.x;
    const int w = tid >> 6, l = tid & 63, quad = l >> 4, l15 = l & 15;
    const int b0 = blockIdx.x * 16;
    const int u = tid & 127, r0 = tid >> 7;

    short8 whf[16], wlf[16];
    #pragma unroll
    for (int nt = 0; nt < 4; ++nt)
        #pragma unroll
        for (int ks = 0; ks < 4; ++ks) {
            size_t NT = (size_t)(w * 4 + nt);
            whf[nt * 4 + ks] = *(const short8*)(whhfG + (((NT * 4 + ks) * 2 + 0) * 64 + l) * 8);
            wlf[nt * 4 + ks] = *(const short8*)(whhfG + (((NT * 4 + ks) * 2 + 1) * 64 + l) * 8);
        }

    float c[4] = {0.f, 0.f, 0.f, 0.f};
    for (int e = tid; e < 16 * HS; e += 512) s_h[e] = 0;
    __syncthreads();

    for (int t = 0; t < 31; ++t) {
        float xgv[16];
        #pragma unroll
        for (int j = 0; j < 4; ++j) {
            size_t base = ((size_t)(b0 + r0 * 4 + j) * PNUM + t) * 512 + u;
            xgv[j * 4 + 0] = xg[base];
            xgv[j * 4 + 1] = xg[base + 128];
            xgv[j * 4 + 2] = xg[base + 256];
            xgv[j * 4 + 3] = xg[base + 384];
        }

        short8 af[4];
        #pragma unroll
        for (int ks = 0; ks < 4; ++ks)
            af[ks] = *(const short8*)&s_h[l15 * HS + ks * 32 + quad * 8];
        f32x4 z = {0.f, 0.f, 0.f, 0.f};
        f32x4 acc[4] = {z, z, z, z};
        #pragma unroll
        for (int nt = 0; nt < 4; ++nt)
            #pragma unroll
            for (int ks = 0; ks < 4; ++ks) {
                acc[nt] = MFMA16(af[ks], whf[nt * 4 + ks], acc[nt]);
                acc[nt] = MFMA16(af[ks], wlf[nt * 4 + ks], acc[nt]);
            }
        #pragma unroll
        for (int nt = 0; nt < 4; ++nt) {
            int n = w * 64 + nt * 16 + l15;
            #pragma unroll
            for (int reg = 0; reg < 4; ++reg)
                s_g2[(quad * 4 + reg) * GS + n] = acc[nt][reg];
        }
        __syncthreads();

        #pragma unroll
        for (int j = 0; j < 4; ++j) {
            int rr = r0 * 4 + j;
            float gi = xgv[j * 4 + 0] + s_g2[rr * GS + u];
            float gf = xgv[j * 4 + 1] + s_g2[rr * GS + 128 + u];
            float gg = xgv[j * 4 + 2] + s_g2[rr * GS + 256 + u];
            float go = xgv[j * 4 + 3] + s_g2[rr * GS + 384 + u];
            float cn = sigf(gf) * c[j] + sigf(gi) * tanhfast(gg);
            float h = sigf(go) * tanhfast(cn);
            c[j] = cn;
            s_h[rr * HS + u] = f2bf(h);
            if (!FINAL)
                out0[((size_t)(b0 + rr) * PNUM + t) * 128 + u] = h;
        }
        __syncthreads();
    }

    if (FINAL) {
        #pragma unroll
        for (int it2 = 0; it2 < 2; ++it2) {
            int item = tid + it2 * 512;
            int rr = item >> 6, uu = item & 63;
            float acc = bc1[uu];
            const float* wv = Wc1 + (size_t)uu * 128;
            #pragma unroll 8
            for (int k = 0; k < 128; ++k) acc += wv[k] * bf2f(s_h[rr * HS + k]);
            s_hid[rr * 68 + uu] = fmaxf(acc, 0.f);
        }
        __syncthreads();
        if (tid < 176) {
            int rr = tid / 11, cc = tid % 11;
            float acc = bc2[cc];
            #pragma unroll
            for (int uu = 0; uu < 64; ++uu) acc += Wc2[cc * 64 + uu] * s_hid[rr * 68 + uu];
            out[(size_t)(b0 + rr) * 11 + cc] = acc;
        }
    }
}

// ---------------------------------------------------------------------------
extern "C" void kernel_launch(void* const* d_in, const int* in_sizes, int n_in,
                              void* d_out, int out_size, void* d_ws, size_t ws_size,
                              hipStream_t stream) {
    (void)in_sizes; (void)n_in; (void)out_size; (void)ws_size;
    const float* I    = (const float*)d_in[0];
    const float* Q    = (const float*)d_in[1];
    const float* ew   = (const float*)d_in[2];
    const float* Wn1  = (const float*)d_in[3];
    const float* bn1  = (const float*)d_in[4];
    const float* Ws1  = (const float*)d_in[5];
    const float* bs1  = (const float*)d_in[6];
    const float* Wn2  = (const float*)d_in[7];
    const float* bn2  = (const float*)d_in[8];
    const float* Ws2  = (const float*)d_in[9];
    const float* bs2  = (const float*)d_in[10];
    const float* Wih0 = (const float*)d_in[11];
    const float* Whh0 = (const float*)d_in[12];
    const float* bih0 = (const float*)d_in[13];
    const float* bhh0 = (const float*)d_in[14];
    const float* Wih1 = (const float*)d_in[15];
    const float* Whh1 = (const float*)d_in[16];
    const float* bih1 = (const float*)d_in[17];
    const float* bhh1 = (const float*)d_in[18];
    const float* Wc1  = (const float*)d_in[19];
    const float* bc1  = (const float*)d_in[20];
    const float* Wc2  = (const float*)d_in[21];
    const float* bc2  = (const float*)d_in[22];
    float* out = (float*)d_out;

    // workspace (floats): ~90.4 MB
    float* wsp   = (float*)d_ws;
    float* adjn  = wsp;                           // 4096
    float* WihT0 = adjn  + 4096;                  // 32768
    float* WihT1 = WihT0 + 32768;                 // 65536
    short* adjfG  = (short*)(WihT1 + 65536);      // 3072 shorts
    short* wcatfG = adjfG + 3072;                 // 16384 shorts
    short* whhf0G = wcatfG + 16384;               // 131072 shorts
    short* whhf1G = whhf0G + 131072;              // 131072 shorts  (=> 140800 floats total)
    float* feats = WihT1 + 65536 + 140800;        // 2031616
    float* out0  = feats + 2031616;               // 4063232
    float* xg    = out0  + 4063232;               // 16252928 (shared by both layers)

    adj_kernel<<<1, 64, 0, stream>>>(ew, adjn);
    prep_kernel<<<522, 256, 0, stream>>>(Wih0, Whh0, Wih1, Whh1, adjn, Ws2, Wn2,
                                         WihT0, WihT1, adjfG, wcatfG, whhf0G, whhf1G);
    sage_mfma<<<SGRID, 256, 0, stream>>>(I, Q, adjn, Wn1, bn1, Ws1, bs1,
                                         bn2, bs2, adjfG, wcatfG, feats);
    gemm512_kernel<64><<<dim3(496, 4), 256, 0, stream>>>(feats, WihT0, bih0, bhh0, xg);
    lstm_mfma<false><<<64, 512, 0, stream>>>(xg, whhf0G, out0,
                                             nullptr, nullptr, nullptr, nullptr, nullptr);
    gemm512_kernel<128><<<dim3(496, 4), 256, 0, stream>>>(out0, WihT1, bih1, bhh1, xg);
    lstm_mfma<true><<<64, 512, 0, stream>>>(xg, whhf1G, nullptr,
                                            Wc1, bc1, Wc2, bc2, out);
}

// Round 5
// 581.005 us; speedup vs baseline: 1.4068x; 1.4068x over previous
//
#include <hip/hip_runtime.h>
#include <hip/hip_bf16.h>
#include <math.h>

#define L_SZ 1024
#define STRIDE_ 32
#define WIN 8
#define PNUM 31
#define NPATCH 31744   // 1024 batches x 31 patches
#define SGRID 768      // 256 CU x 3 blocks/CU, all co-resident

// LDS row strides (in shorts). dword strides = 36/68 = 4 mod 32 -> 2-way banks (free).
#define X1TS 72
#define CAS  136

typedef __attribute__((ext_vector_type(8))) short short8;
typedef __attribute__((ext_vector_type(4))) short short4v;
typedef __attribute__((ext_vector_type(4))) float f32x4;

#define MFMA16(a, b, c) __builtin_amdgcn_mfma_f32_16x16x32_bf16(a, b, c, 0, 0, 0)

__device__ __forceinline__ float sigf(float x) { return 1.0f / (1.0f + __expf(-x)); }
__device__ __forceinline__ float tanhfast(float x) {
    float ax = fabsf(x);
    float t = __expf(-2.0f * ax);
    return copysignf((1.0f - t) / (1.0f + t), x);
}
__device__ __forceinline__ short f2bf(float f) {
    __hip_bfloat16 h = __float2bfloat16(f);   // RNE
    return *reinterpret_cast<short*>(&h);
}
__device__ __forceinline__ float bf2f(short s) {
    __hip_bfloat16 h = *reinterpret_cast<__hip_bfloat16*>(&s);
    return __bfloat162float(h);
}
__device__ __forceinline__ float f4c(float4 v, int k) {
    return k == 0 ? v.x : (k == 1 ? v.y : (k == 2 ? v.z : v.w));
}
__device__ __forceinline__ void fma4(float4& acc, float s, float4 v) {
    acc.x += s * v.x; acc.y += s * v.y; acc.z += s * v.z; acc.w += s * v.w;
}

// ---------------------------------------------------------------------------
// adjn[i][j] = sigmoid(ew[i][j]) * mask(|i-j|<=8, i!=j) * deg_inv[i]
// ---------------------------------------------------------------------------
__global__ void adj_kernel(const float* __restrict__ ew, float* __restrict__ adjn) {
    int i = threadIdx.x;
    if (i >= 64) return;
    float sum = 0.f;
    for (int j = 0; j < 64; ++j) {
        int d = i - j; d = d < 0 ? -d : d;
        float a = (d <= WIN && d != 0) ? sigf(ew[i * 64 + j]) : 0.f;
        sum += a;
    }
    float dinv = (sum > 0.f) ? 1.0f / sum : 0.f;
    for (int j = 0; j < 64; ++j) {
        int d = i - j; d = d < 0 ? -d : d;
        float a = (d <= WIN && d != 0) ? sigf(ew[i * 64 + j]) : 0.f;
        adjn[i * 64 + j] = a * dinv;
    }
}

// ---------------------------------------------------------------------------
// prep (unchanged from R15):
//   blocks   0..127 : Wih0T | 128..383 : Wih1T | 384..393 : sage frags
//   blocks 394..457 : Whh0 frags hi/lo | 458..521 : Whh1 frags hi/lo
// ---------------------------------------------------------------------------
__global__ void prep_kernel(const float* __restrict__ Wih0, const float* __restrict__ Whh0,
                            const float* __restrict__ Wih1, const float* __restrict__ Whh1,
                            const float* __restrict__ adjn,
                            const float* __restrict__ Ws2, const float* __restrict__ Wn2,
                            float* __restrict__ Wih0T, float* __restrict__ Wih1T,
                            short* __restrict__ adjfG, short* __restrict__ wcatfG,
                            short* __restrict__ whhf0G, short* __restrict__ whhf1G) {
    int bid = blockIdx.x, tid = threadIdx.x;
    if (bid < 128) {
        int e = bid * 256 + tid;
        int k = e >> 9, j = e & 511;
        Wih0T[e] = Wih0[j * 64 + k];
        return;
    }
    if (bid < 384) {
        int e = (bid - 128) * 256 + tid;
        int k = e >> 9, j = e & 511;
        Wih1T[e] = Wih1[j * 128 + k];
        return;
    }
    if (bid < 394) {
        int t = (bid - 384) * 256 + tid;
        if (t >= 2432) return;
        int f = t >> 6, l = t & 63;
        int q = l >> 4, l15 = l & 15;
        short8 v;
        if (f < 6) {
            const int ntT[6] = {0, 1, 1, 2, 2, 3};
            const int ksT[6] = {0, 0, 1, 0, 1, 1};
            int row = l15 + 16 * ntT[f], col = 8 * q + 32 * ksT[f];
            #pragma unroll
            for (int e = 0; e < 8; ++e)
                v[e] = f2bf(adjn[row * 64 + col + e]);
            *(short8*)(adjfG + ((size_t)f * 64 + l) * 8) = v;
        } else {
            int fi = f - 6;
            int isLo = fi >= 16;
            int ff = isLo ? fi - 16 : fi;
            int nt = ff >> 2, ks = ff & 3;
            int oo = l15 + 16 * nt;
            #pragma unroll
            for (int e = 0; e < 8; ++e) {
                int k = 32 * ks + 8 * q + e;
                float src = (k < 64) ? Ws2[oo * 64 + k] : Wn2[oo * 64 + (k - 64)];
                short hi = f2bf(src);
                v[e] = isLo ? f2bf(src - bf2f(hi)) : hi;
            }
            *(short8*)(wcatfG + ((size_t)fi * 64 + l) * 8) = v;
        }
        return;
    }
    {
        int layer = (bid < 458) ? 0 : 1;
        int base = layer ? 458 : 394;
        const float* Whh = layer ? Whh1 : Whh0;
        short* dst = layer ? whhf1G : whhf0G;
        int t = (bid - base) * 256 + tid;    // 0..16383
        int frag = t >> 6, l = t & 63;
        int hl = frag & 1, ks = (frag >> 1) & 3, NT = frag >> 3;
        int g = NT * 16 + (l & 15);
        int kbase = ks * 32 + (l >> 4) * 8;
        short8 v;
        #pragma unroll
        for (int e = 0; e < 8; ++e) {
            float src = Whh[(size_t)g * 128 + kbase + e];
            short hi = f2bf(src);
            v[e] = hl ? f2bf(src - bf2f(hi)) : hi;
        }
        *(short8*)(dst + (size_t)t * 8) = v;
    }
}

// ---------------------------------------------------------------------------
// Persistent fused SAGE, bf16 MFMA.
// R20: R19 structure, (256,2) launch bounds. R19's (256,3) triggered the
// allocator pathology: it kept VGPR=84 (R18's level) and spilled the ~26
// new loop-invariants (areg/shuffle/prefetch temps) to scratch, reloading
// them every iter -> FETCH 862 MB, 426 us. Empirically on this kernel the
// allocator honors a (256,2) budget (R15: 128 regs, no spill) but refuses
// to grow past ~84 under (256,3) and past 64 under (256,4). With (256,2)
// the license is 256 regs (need ~110-130 -> no spill) and occupancy is
// LDS-capped: 53,248 B x 3 = 159,744 <= 163,840 -> 3 blocks/CU, matching
// the 768-block grid. Structure (bit-identical math, same term order):
//  (1) adjn band -> 17 regs, hoisted (patch-invariant).
//  (2) n0 via __shfl, fixed-trip d=-8..8 fully unrolled; out-of-band terms
//      multiply the EXACT 0.0f band weights -> bit-identical sum.
//  (3) next-patch x0 prefetch in regs (hidden under phase1+MFMA).
//  (4) s_x1T/s_cat double-buffered -> 2 barriers/iter.
// ---------------------------------------------------------------------------
__launch_bounds__(256, 2)
__global__ void sage_mfma(const float* __restrict__ I, const float* __restrict__ Q,
                          const float* __restrict__ adjn,
                          const float* __restrict__ Wn1, const float* __restrict__ bn1,
                          const float* __restrict__ Ws1, const float* __restrict__ bs1,
                          const float* __restrict__ bn2, const float* __restrict__ bs2,
                          const short* __restrict__ adjfG, const short* __restrict__ wcatfG,
                          float* __restrict__ feats) {
    __shared__ __align__(16) short s_x1T[2][64 * X1TS];  // x1^T [o][i] bf16
    __shared__ __align__(16) short s_cat[2][64 * CAS];   // [i][x1|n1] bf16

    const int tid = threadIdx.x;
    const int w = tid >> 6, l = tid & 63, q = l >> 4, l15 = l & 15;

    // adj frags for THIS wave's i-tile (band): w0:{ks0}, w1/w2:{ks0,ks1}, w3:{ks1}
    const bool hasKs0 = (w <= 2);
    const bool hasKs1 = (w >= 1);
    const int idx0 = (w == 0) ? 0 : (w == 1 ? 1 : 3);    // frag idx for (nt=w, ks=0)
    const int idx1 = (w == 1) ? 2 : (w == 2 ? 4 : 5);    // frag idx for (nt=w, ks=1)
    short8 adjB0 = {}, adjB1 = {};
    if (hasKs0) adjB0 = *(const short8*)(adjfG + ((size_t)idx0 * 64 + l) * 8);
    if (hasKs1) adjB1 = *(const short8*)(adjfG + ((size_t)idx1 * 64 + l) * 8);

    // weight frags for THIS wave's o-tile (nt = w): 8 frags = 32 VGPRs
    short8 whf[4], wlf[4];
    #pragma unroll
    for (int ks = 0; ks < 4; ++ks) {
        whf[ks] = *(const short8*)(wcatfG + ((size_t)(w * 4 + ks) * 64 + l) * 8);
        wlf[ks] = *(const short8*)(wcatfG + ((size_t)(w * 4 + ks + 16) * 64 + l) * 8);
    }
    // bias for this wave's output channel (loop-invariant)
    const int oo = l15 + 16 * w;
    const float bo = bs2[oo] + bn2[oo];

    // (1) adjn band in registers: lane l = row i; zeros outside [0,64)
    float areg[17];
    #pragma unroll
    for (int d = 0; d < 17; ++d) {
        int j = l + d - WIN;
        areg[d] = (j >= 0 && j < 64) ? adjn[l * 64 + j] : 0.f;
    }

    // initial x0 (lane l holds column i = l; same in all 4 waves, L1-broadcast)
    int m = blockIdx.x;
    float x0a, x0b;
    {
        int b = m / PNUM, p = m % PNUM;
        x0a = I[(size_t)b * L_SZ + p * STRIDE_ + l];
        x0b = Q[(size_t)b * L_SZ + p * STRIDE_ + l];
    }

    int pb = 0;
    while (m < NPATCH) {
        // (3) prefetch next patch's x0 — independent, hides global latency
        const int mn = m + SGRID;
        float nxa = 0.f, nxb = 0.f;
        if (mn < NPATCH) {
            int bn = mn / PNUM, pn = mn % PNUM;
            nxa = I[(size_t)bn * L_SZ + pn * STRIDE_ + l];
            nxb = Q[(size_t)bn * L_SZ + pn * STRIDE_ + l];
        }

        short* __restrict__ x1T = s_x1T[pb];
        short* __restrict__ cat = s_cat[pb];

        // ---- Phase 1: n0 via shuffles, x1 = relu(...) ----
        {
            // (2) fixed-trip window; out-of-band areg == 0.0f exactly
            float n0a = 0.f, n0b = 0.f;
            #pragma unroll
            for (int d = 0; d < 17; ++d) {
                int j = l + d - WIN;
                float xa = __shfl(x0a, j, 64);
                float xb = __shfl(x0b, j, 64);
                n0a += areg[d] * xa;
                n0b += areg[d] * xb;
            }
            union { short s[16]; short8 v[2]; } pk;
            #pragma unroll
            for (int t = 0; t < 16; ++t) {
                int o = w * 16 + t;
                float2 wsv = ((const float2*)Ws1)[o];
                float2 wnv = ((const float2*)Wn1)[o];
                float v = bs1[o] + bn1[o] + wsv.x * x0a + wsv.y * x0b
                                          + wnv.x * n0a + wnv.y * n0b;
                v = fmaxf(v, 0.f);
                short bv = f2bf(v);
                x1T[o * X1TS + l] = bv;
                pk.s[t] = bv;
            }
            *(short8*)&cat[l * CAS + w * 16]     = pk.v[0];
            *(short8*)&cat[l * CAS + w * 16 + 8] = pk.v[1];
        }
        __syncthreads();   // barrier 1: x1T/cat(x1) visible to all waves

        // ---- MFMA#1: n1^T for i-tile w. A = x1T o-tiles, B = adj cols. ----
        #pragma unroll
        for (int ot = 0; ot < 4; ++ot) {
            f32x4 c = {0.f, 0.f, 0.f, 0.f};
            if (hasKs0) {
                short8 a = *(const short8*)&x1T[(16 * ot + l15) * X1TS + 8 * q];
                c = MFMA16(a, adjB0, c);
            }
            if (hasKs1) {
                short8 a = *(const short8*)&x1T[(16 * ot + l15) * X1TS + 8 * q + 32];
                c = MFMA16(a, adjB1, c);
            }
            // C: col i = 16w+l15 (lane), rows o = 16ot+4q+reg -> b64 write
            short4v nv;
            nv[0] = f2bf(c[0]); nv[1] = f2bf(c[1]);
            nv[2] = f2bf(c[2]); nv[3] = f2bf(c[3]);
            *(short4v*)&cat[(16 * w + l15) * CAS + 64 + 16 * ot + 4 * q] = nv;
        }
        __syncthreads();   // barrier 2: n1 consumed cross-wave

        // ---- MFMA#2: wave w owns o-tile nt=w; loop all 4 i-tiles ----
        {
            f32x4 z = {0.f, 0.f, 0.f, 0.f};
            f32x4 acc2[4] = {z, z, z, z};
            #pragma unroll
            for (int it2 = 0; it2 < 4; ++it2) {
                short8 a2[4];
                #pragma unroll
                for (int ks = 0; ks < 4; ++ks)
                    a2[ks] = *(const short8*)&cat[(16 * it2 + l15) * CAS + 32 * ks + 8 * q];
                #pragma unroll
                for (int ks = 0; ks < 4; ++ks) {
                    acc2[it2] = MFMA16(a2[ks], whf[ks], acc2[it2]);
                    acc2[it2] = MFMA16(a2[ks], wlf[ks], acc2[it2]);
                }
            }
            float total = 0.f;
            #pragma unroll
            for (int it2 = 0; it2 < 4; ++it2) {
                float s = fmaxf(acc2[it2][0] + bo, 0.f) + fmaxf(acc2[it2][1] + bo, 0.f)
                        + fmaxf(acc2[it2][2] + bo, 0.f) + fmaxf(acc2[it2][3] + bo, 0.f);
                s += __shfl_xor(s, 16);
                s += __shfl_xor(s, 32);
                total += s;           // ((s0+s1)+s2)+s3 — same order as before
            }
            if (l < 16)
                feats[(size_t)m * 64 + 16 * w + l15] = total;
        }
        // no trailing barrier: next iter writes buffer pb^1; the two collective
        // barriers per iter prevent any wave from lapping into this buffer.
        x0a = nxa; x0b = nxb; m = mn; pb ^= 1;
    }
}

// ---------------------------------------------------------------------------
// GEMM: C[M x 512] = A[M x K] @ BT[K x 512] + bias1 + bias2  (verified)
// ---------------------------------------------------------------------------
template <int K>
__launch_bounds__(256, 2)
__global__ void gemm512_kernel(const float* __restrict__ A, const float* __restrict__ BT,
                               const float* __restrict__ bias1, const float* __restrict__ bias2,
                               float* __restrict__ C) {
    constexpr int K4 = K / 4;
    __shared__ __align__(16) float s_a[64 * K];
    const int tid = threadIdx.x;
    const int m0 = blockIdx.x * 64;
    const int j0 = blockIdx.y * 128;

    const float4* Ag = (const float4*)A;
    for (int e = tid; e < 16 * K; e += 256) {
        int row = e / K4, c = e % K4;
        ((float4*)s_a)[row * K4 + (c ^ ((row >> 2) & 7))] = Ag[(size_t)(m0 + row) * K4 + c];
    }
    __syncthreads();

    const int ti = tid >> 4, tj = tid & 15;
    const int swz = ti & 7;
    const int j = j0 + tj * 8;
    const int jb = (j0 >> 2) + tj * 2;
    const float4* BT4 = (const float4*)BT;

    float4 accL[4], accH[4];
    #pragma unroll
    for (int ii = 0; ii < 4; ++ii) {
        accL[ii] = make_float4(0.f, 0.f, 0.f, 0.f);
        accH[ii] = make_float4(0.f, 0.f, 0.f, 0.f);
    }
    for (int c = 0; c < K4; ++c) {
        float4 a4[4];
        #pragma unroll
        for (int ii = 0; ii < 4; ++ii)
            a4[ii] = ((const float4*)s_a)[(4 * ti + ii) * K4 + (c ^ swz)];
        #pragma unroll
        for (int kk = 0; kk < 4; ++kk) {
            float4 b1 = BT4[(size_t)(c * 4 + kk) * 128 + jb];
            float4 b2 = BT4[(size_t)(c * 4 + kk) * 128 + jb + 1];
            #pragma unroll
            for (int ii = 0; ii < 4; ++ii) {
                float av = f4c(a4[ii], kk);
                fma4(accL[ii], av, b1);
                fma4(accH[ii], av, b2);
            }
        }
    }
    float4 bL = make_float4(bias1[j] + bias2[j], bias1[j + 1] + bias2[j + 1],
                            bias1[j + 2] + bias2[j + 2], bias1[j + 3] + bias2[j + 3]);
    float4 bH = make_float4(bias1[j + 4] + bias2[j + 4], bias1[j + 5] + bias2[j + 5],
                            bias1[j + 6] + bias2[j + 6], bias1[j + 7] + bias2[j + 7]);
    #pragma unroll
    for (int ii = 0; ii < 4; ++ii) {
        size_t row = (size_t)(m0 + 4 * ti + ii);
        float4 oL = make_float4(accL[ii].x + bL.x, accL[ii].y + bL.y,
                                accL[ii].z + bL.z, accL[ii].w + bL.w);
        float4 oH = make_float4(accH[ii].x + bH.x, accH[ii].y + bH.y,
                                accH[ii].z + bH.z, accH[ii].w + bH.w);
        ((float4*)C)[(row * 512 + j) >> 2] = oL;
        ((float4*)C)[(row * 512 + j + 4) >> 2] = oH;
    }
}

// ---------------------------------------------------------------------------
// LSTM recurrence v4: MFMA (unchanged from R14/R15).
// ---------------------------------------------------------------------------
#define HS 136    // s_h row stride in shorts (68 dwords = 4 mod 32)
#define GS 516    // s_g2 row stride in floats (516 = 4 mod 32, 16B-mult)

template <bool FINAL>
__launch_bounds__(512)
__global__ void lstm_mfma(const float* __restrict__ xg, const short* __restrict__ whhfG,
                          float* __restrict__ out0,
                          const float* __restrict__ Wc1, const float* __restrict__ bc1,
                          const float* __restrict__ Wc2, const float* __restrict__ bc2,
                          float* __restrict__ out) {
    __shared__ __align__(16) short s_h[16 * HS];    // h bf16 [m][k]
    __shared__ __align__(16) float s_g2[16 * GS];   // mfma gates fp32 [m][n]
    __shared__ __align__(16) float s_hid[16 * 68];
    const int tid = threadIdx.x;
    const int w = tid >> 6, l = tid & 63, quad = l >> 4, l15 = l & 15;
    const int b0 = blockIdx.x * 16;
    const int u = tid & 127, r0 = tid >> 7;

    short8 whf[16], wlf[16];
    #pragma unroll
    for (int nt = 0; nt < 4; ++nt)
        #pragma unroll
        for (int ks = 0; ks < 4; ++ks) {
            size_t NT = (size_t)(w * 4 + nt);
            whf[nt * 4 + ks] = *(const short8*)(whhfG + (((NT * 4 + ks) * 2 + 0) * 64 + l) * 8);
            wlf[nt * 4 + ks] = *(const short8*)(whhfG + (((NT * 4 + ks) * 2 + 1) * 64 + l) * 8);
        }

    float c[4] = {0.f, 0.f, 0.f, 0.f};
    for (int e = tid; e < 16 * HS; e += 512) s_h[e] = 0;
    __syncthreads();

    for (int t = 0; t < 31; ++t) {
        float xgv[16];
        #pragma unroll
        for (int j = 0; j < 4; ++j) {
            size_t base = ((size_t)(b0 + r0 * 4 + j) * PNUM + t) * 512 + u;
            xgv[j * 4 + 0] = xg[base];
            xgv[j * 4 + 1] = xg[base + 128];
            xgv[j * 4 + 2] = xg[base + 256];
            xgv[j * 4 + 3] = xg[base + 384];
        }

        short8 af[4];
        #pragma unroll
        for (int ks = 0; ks < 4; ++ks)
            af[ks] = *(const short8*)&s_h[l15 * HS + ks * 32 + quad * 8];
        f32x4 z = {0.f, 0.f, 0.f, 0.f};
        f32x4 acc[4] = {z, z, z, z};
        #pragma unroll
        for (int nt = 0; nt < 4; ++nt)
            #pragma unroll
            for (int ks = 0; ks < 4; ++ks) {
                acc[nt] = MFMA16(af[ks], whf[nt * 4 + ks], acc[nt]);
                acc[nt] = MFMA16(af[ks], wlf[nt * 4 + ks], acc[nt]);
            }
        #pragma unroll
        for (int nt = 0; nt < 4; ++nt) {
            int n = w * 64 + nt * 16 + l15;
            #pragma unroll
            for (int reg = 0; reg < 4; ++reg)
                s_g2[(quad * 4 + reg) * GS + n] = acc[nt][reg];
        }
        __syncthreads();

        #pragma unroll
        for (int j = 0; j < 4; ++j) {
            int rr = r0 * 4 + j;
            float gi = xgv[j * 4 + 0] + s_g2[rr * GS + u];
            float gf = xgv[j * 4 + 1] + s_g2[rr * GS + 128 + u];
            float gg = xgv[j * 4 + 2] + s_g2[rr * GS + 256 + u];
            float go = xgv[j * 4 + 3] + s_g2[rr * GS + 384 + u];
            float cn = sigf(gf) * c[j] + sigf(gi) * tanhfast(gg);
            float h = sigf(go) * tanhfast(cn);
            c[j] = cn;
            s_h[rr * HS + u] = f2bf(h);
            if (!FINAL)
                out0[((size_t)(b0 + rr) * PNUM + t) * 128 + u] = h;
        }
        __syncthreads();
    }

    if (FINAL) {
        #pragma unroll
        for (int it2 = 0; it2 < 2; ++it2) {
            int item = tid + it2 * 512;
            int rr = item >> 6, uu = item & 63;
            float acc = bc1[uu];
            const float* wv = Wc1 + (size_t)uu * 128;
            #pragma unroll 8
            for (int k = 0; k < 128; ++k) acc += wv[k] * bf2f(s_h[rr * HS + k]);
            s_hid[rr * 68 + uu] = fmaxf(acc, 0.f);
        }
        __syncthreads();
        if (tid < 176) {
            int rr = tid / 11, cc = tid % 11;
            float acc = bc2[cc];
            #pragma unroll
            for (int uu = 0; uu < 64; ++uu) acc += Wc2[cc * 64 + uu] * s_hid[rr * 68 + uu];
            out[(size_t)(b0 + rr) * 11 + cc] = acc;
        }
    }
}

// ---------------------------------------------------------------------------
extern "C" void kernel_launch(void* const* d_in, const int* in_sizes, int n_in,
                              void* d_out, int out_size, void* d_ws, size_t ws_size,
                              hipStream_t stream) {
    (void)in_sizes; (void)n_in; (void)out_size; (void)ws_size;
    const float* I    = (const float*)d_in[0];
    const float* Q    = (const float*)d_in[1];
    const float* ew   = (const float*)d_in[2];
    const float* Wn1  = (const float*)d_in[3];
    const float* bn1  = (const float*)d_in[4];
    const float* Ws1  = (const float*)d_in[5];
    const float* bs1  = (const float*)d_in[6];
    const float* Wn2  = (const float*)d_in[7];
    const float* bn2  = (const float*)d_in[8];
    const float* Ws2  = (const float*)d_in[9];
    const float* bs2  = (const float*)d_in[10];
    const float* Wih0 = (const float*)d_in[11];
    const float* Whh0 = (const float*)d_in[12];
    const float* bih0 = (const float*)d_in[13];
    const float* bhh0 = (const float*)d_in[14];
    const float* Wih1 = (const float*)d_in[15];
    const float* Whh1 = (const float*)d_in[16];
    const float* bih1 = (const float*)d_in[17];
    const float* bhh1 = (const float*)d_in[18];
    const float* Wc1  = (const float*)d_in[19];
    const float* bc1  = (const float*)d_in[20];
    const float* Wc2  = (const float*)d_in[21];
    const float* bc2  = (const float*)d_in[22];
    float* out = (float*)d_out;

    // workspace (floats): ~90.4 MB
    float* wsp   = (float*)d_ws;
    float* adjn  = wsp;                           // 4096
    float* WihT0 = adjn  + 4096;                  // 32768
    float* WihT1 = WihT0 + 32768;                 // 65536
    short* adjfG  = (short*)(WihT1 + 65536);      // 3072 shorts
    short* wcatfG = adjfG + 3072;                 // 16384 shorts
    short* whhf0G = wcatfG + 16384;               // 131072 shorts
    short* whhf1G = whhf0G + 131072;              // 131072 shorts  (=> 140800 floats total)
    float* feats = WihT1 + 65536 + 140800;        // 2031616
    float* out0  = feats + 2031616;               // 4063232
    float* xg    = out0  + 4063232;               // 16252928 (shared by both layers)

    adj_kernel<<<1, 64, 0, stream>>>(ew, adjn);
    prep_kernel<<<522, 256, 0, stream>>>(Wih0, Whh0, Wih1, Whh1, adjn, Ws2, Wn2,
                                         WihT0, WihT1, adjfG, wcatfG, whhf0G, whhf1G);
    sage_mfma<<<SGRID, 256, 0, stream>>>(I, Q, adjn, Wn1, bn1, Ws1, bs1,
                                         bn2, bs2, adjfG, wcatfG, feats);
    gemm512_kernel<64><<<dim3(496, 4), 256, 0, stream>>>(feats, WihT0, bih0, bhh0, xg);
    lstm_mfma<false><<<64, 512, 0, stream>>>(xg, whhf0G, out0,
                                             nullptr, nullptr, nullptr, nullptr, nullptr);
    gemm512_kernel<128><<<dim3(496, 4), 256, 0, stream>>>(out0, WihT1, bih1, bhh1, xg);
    lstm_mfma<true><<<64, 512, 0, stream>>>(xg, whhf1G, nullptr,
                                            Wc1, bc1, Wc2, bc2, out);
}

// Round 6
// 578.605 us; speedup vs baseline: 1.4126x; 1.0041x over previous
//
#include <hip/hip_runtime.h>
#include <hip/hip_bf16.h>
#include <math.h>

#define L_SZ 1024
#define STRIDE_ 32
#define WIN 8
#define PNUM 31
#define NPATCH 31744   // 1024 batches x 31 patches
#define SGRID 768      // 256 CU x 3 blocks/CU, all co-resident

// LDS row strides (in shorts). dword strides = 36/68 = 4 mod 32 -> 2-way banks (free).
#define X1TS 72
#define CAS  136

typedef __attribute__((ext_vector_type(8))) short short8;
typedef __attribute__((ext_vector_type(4))) short short4v;
typedef __attribute__((ext_vector_type(4))) float f32x4;

#define MFMA16(a, b, c) __builtin_amdgcn_mfma_f32_16x16x32_bf16(a, b, c, 0, 0, 0)

__device__ __forceinline__ float sigf(float x) { return 1.0f / (1.0f + __expf(-x)); }
__device__ __forceinline__ float tanhfast(float x) {
    float ax = fabsf(x);
    float t = __expf(-2.0f * ax);
    return copysignf((1.0f - t) / (1.0f + t), x);
}
__device__ __forceinline__ short f2bf(float f) {
    __hip_bfloat16 h = __float2bfloat16(f);   // RNE
    return *reinterpret_cast<short*>(&h);
}
__device__ __forceinline__ float bf2f(short s) {
    __hip_bfloat16 h = *reinterpret_cast<__hip_bfloat16*>(&s);
    return __bfloat162float(h);
}
__device__ __forceinline__ float f4c(float4 v, int k) {
    return k == 0 ? v.x : (k == 1 ? v.y : (k == 2 ? v.z : v.w));
}
__device__ __forceinline__ void fma4(float4& acc, float s, float4 v) {
    acc.x += s * v.x; acc.y += s * v.y; acc.z += s * v.z; acc.w += s * v.w;
}

// ---------------------------------------------------------------------------
// adjn[i][j] = sigmoid(ew[i][j]) * mask(|i-j|<=8, i!=j) * deg_inv[i]
// ---------------------------------------------------------------------------
__global__ void adj_kernel(const float* __restrict__ ew, float* __restrict__ adjn) {
    int i = threadIdx.x;
    if (i >= 64) return;
    float sum = 0.f;
    for (int j = 0; j < 64; ++j) {
        int d = i - j; d = d < 0 ? -d : d;
        float a = (d <= WIN && d != 0) ? sigf(ew[i * 64 + j]) : 0.f;
        sum += a;
    }
    float dinv = (sum > 0.f) ? 1.0f / sum : 0.f;
    for (int j = 0; j < 64; ++j) {
        int d = i - j; d = d < 0 ? -d : d;
        float a = (d <= WIN && d != 0) ? sigf(ew[i * 64 + j]) : 0.f;
        adjn[i * 64 + j] = a * dinv;
    }
}

// ---------------------------------------------------------------------------
// prep (unchanged from R15):
//   blocks   0..127 : Wih0T | 128..383 : Wih1T | 384..393 : sage frags
//   blocks 394..457 : Whh0 frags hi/lo | 458..521 : Whh1 frags hi/lo
// ---------------------------------------------------------------------------
__global__ void prep_kernel(const float* __restrict__ Wih0, const float* __restrict__ Whh0,
                            const float* __restrict__ Wih1, const float* __restrict__ Whh1,
                            const float* __restrict__ adjn,
                            const float* __restrict__ Ws2, const float* __restrict__ Wn2,
                            float* __restrict__ Wih0T, float* __restrict__ Wih1T,
                            short* __restrict__ adjfG, short* __restrict__ wcatfG,
                            short* __restrict__ whhf0G, short* __restrict__ whhf1G) {
    int bid = blockIdx.x, tid = threadIdx.x;
    if (bid < 128) {
        int e = bid * 256 + tid;
        int k = e >> 9, j = e & 511;
        Wih0T[e] = Wih0[j * 64 + k];
        return;
    }
    if (bid < 384) {
        int e = (bid - 128) * 256 + tid;
        int k = e >> 9, j = e & 511;
        Wih1T[e] = Wih1[j * 128 + k];
        return;
    }
    if (bid < 394) {
        int t = (bid - 384) * 256 + tid;
        if (t >= 2432) return;
        int f = t >> 6, l = t & 63;
        int q = l >> 4, l15 = l & 15;
        short8 v;
        if (f < 6) {
            const int ntT[6] = {0, 1, 1, 2, 2, 3};
            const int ksT[6] = {0, 0, 1, 0, 1, 1};
            int row = l15 + 16 * ntT[f], col = 8 * q + 32 * ksT[f];
            #pragma unroll
            for (int e = 0; e < 8; ++e)
                v[e] = f2bf(adjn[row * 64 + col + e]);
            *(short8*)(adjfG + ((size_t)f * 64 + l) * 8) = v;
        } else {
            int fi = f - 6;
            int isLo = fi >= 16;
            int ff = isLo ? fi - 16 : fi;
            int nt = ff >> 2, ks = ff & 3;
            int oo = l15 + 16 * nt;
            #pragma unroll
            for (int e = 0; e < 8; ++e) {
                int k = 32 * ks + 8 * q + e;
                float src = (k < 64) ? Ws2[oo * 64 + k] : Wn2[oo * 64 + (k - 64)];
                short hi = f2bf(src);
                v[e] = isLo ? f2bf(src - bf2f(hi)) : hi;
            }
            *(short8*)(wcatfG + ((size_t)fi * 64 + l) * 8) = v;
        }
        return;
    }
    {
        int layer = (bid < 458) ? 0 : 1;
        int base = layer ? 458 : 394;
        const float* Whh = layer ? Whh1 : Whh0;
        short* dst = layer ? whhf1G : whhf0G;
        int t = (bid - base) * 256 + tid;    // 0..16383
        int frag = t >> 6, l = t & 63;
        int hl = frag & 1, ks = (frag >> 1) & 3, NT = frag >> 3;
        int g = NT * 16 + (l & 15);
        int kbase = ks * 32 + (l >> 4) * 8;
        short8 v;
        #pragma unroll
        for (int e = 0; e < 8; ++e) {
            float src = Whh[(size_t)g * 128 + kbase + e];
            short hi = f2bf(src);
            v[e] = hl ? f2bf(src - bf2f(hi)) : hi;
        }
        *(short8*)(dst + (size_t)t * 8) = v;
    }
}

// ---------------------------------------------------------------------------
// Persistent fused SAGE, bf16 MFMA.
// R21: reclaim 3 blocks/CU. R20 (53,248 B LDS) ran at time-avg 18.6% occ =
// 1.5 blocks/CU: only 2 co-resident (LDS granule rounding), so the 768-block
// grid serialized into 512 + 256 cohorts with half the machine idle in the
// tail. Fix: s_x1T does NOT need double-buffering — its lifetime is
// phase1 -> MFMA#1, fully contained between barrier 1 and barrier 2; every
// wave's next-iter phase1 write lands after barrier 2. Only s_cat keeps the
// double buffer (MFMA#2 reads cat[pb] with no trailing barrier while other
// waves write cat[pb^1]). LDS = 9,216 + 2x17,408 = 44,032 B -> even at an
// 8 KB granule (49,152) 3 blocks = 147,456 <= 163,840. Math, operand
// layouts, barrier count (2/iter) unchanged -> bit-identical.
// R20 baseline: 201 us, VGPR 116, FETCH 8.2 MB (no spill).
// ---------------------------------------------------------------------------
__launch_bounds__(256, 2)
__global__ void sage_mfma(const float* __restrict__ I, const float* __restrict__ Q,
                          const float* __restrict__ adjn,
                          const float* __restrict__ Wn1, const float* __restrict__ bn1,
                          const float* __restrict__ Ws1, const float* __restrict__ bs1,
                          const float* __restrict__ bn2, const float* __restrict__ bs2,
                          const short* __restrict__ adjfG, const short* __restrict__ wcatfG,
                          float* __restrict__ feats) {
    __shared__ __align__(16) short s_x1T[64 * X1TS];     // x1^T [o][i] bf16 (single)
    __shared__ __align__(16) short s_cat[2][64 * CAS];   // [i][x1|n1] bf16 (double)

    const int tid = threadIdx.x;
    const int w = tid >> 6, l = tid & 63, q = l >> 4, l15 = l & 15;

    // adj frags for THIS wave's i-tile (band): w0:{ks0}, w1/w2:{ks0,ks1}, w3:{ks1}
    const bool hasKs0 = (w <= 2);
    const bool hasKs1 = (w >= 1);
    const int idx0 = (w == 0) ? 0 : (w == 1 ? 1 : 3);    // frag idx for (nt=w, ks=0)
    const int idx1 = (w == 1) ? 2 : (w == 2 ? 4 : 5);    // frag idx for (nt=w, ks=1)
    short8 adjB0 = {}, adjB1 = {};
    if (hasKs0) adjB0 = *(const short8*)(adjfG + ((size_t)idx0 * 64 + l) * 8);
    if (hasKs1) adjB1 = *(const short8*)(adjfG + ((size_t)idx1 * 64 + l) * 8);

    // weight frags for THIS wave's o-tile (nt = w): 8 frags = 32 VGPRs
    short8 whf[4], wlf[4];
    #pragma unroll
    for (int ks = 0; ks < 4; ++ks) {
        whf[ks] = *(const short8*)(wcatfG + ((size_t)(w * 4 + ks) * 64 + l) * 8);
        wlf[ks] = *(const short8*)(wcatfG + ((size_t)(w * 4 + ks + 16) * 64 + l) * 8);
    }
    // bias for this wave's output channel (loop-invariant)
    const int oo = l15 + 16 * w;
    const float bo = bs2[oo] + bn2[oo];

    // adjn band in registers: lane l = row i; zeros outside [0,64)
    float areg[17];
    #pragma unroll
    for (int d = 0; d < 17; ++d) {
        int j = l + d - WIN;
        areg[d] = (j >= 0 && j < 64) ? adjn[l * 64 + j] : 0.f;
    }

    // initial x0 (lane l holds column i = l; same in all 4 waves, L1-broadcast)
    int m = blockIdx.x;
    float x0a, x0b;
    {
        int b = m / PNUM, p = m % PNUM;
        x0a = I[(size_t)b * L_SZ + p * STRIDE_ + l];
        x0b = Q[(size_t)b * L_SZ + p * STRIDE_ + l];
    }

    int pb = 0;
    while (m < NPATCH) {
        // prefetch next patch's x0 — independent, hides global latency
        const int mn = m + SGRID;
        float nxa = 0.f, nxb = 0.f;
        if (mn < NPATCH) {
            int bn = mn / PNUM, pn = mn % PNUM;
            nxa = I[(size_t)bn * L_SZ + pn * STRIDE_ + l];
            nxb = Q[(size_t)bn * L_SZ + pn * STRIDE_ + l];
        }

        short* __restrict__ cat = s_cat[pb];

        // ---- Phase 1: n0 via shuffles, x1 = relu(...) ----
        {
            // fixed-trip window; out-of-band areg == 0.0f exactly
            float n0a = 0.f, n0b = 0.f;
            #pragma unroll
            for (int d = 0; d < 17; ++d) {
                int j = l + d - WIN;
                float xa = __shfl(x0a, j, 64);
                float xb = __shfl(x0b, j, 64);
                n0a += areg[d] * xa;
                n0b += areg[d] * xb;
            }
            union { short s[16]; short8 v[2]; } pk;
            #pragma unroll
            for (int t = 0; t < 16; ++t) {
                int o = w * 16 + t;
                float2 wsv = ((const float2*)Ws1)[o];
                float2 wnv = ((const float2*)Wn1)[o];
                float v = bs1[o] + bn1[o] + wsv.x * x0a + wsv.y * x0b
                                          + wnv.x * n0a + wnv.y * n0b;
                v = fmaxf(v, 0.f);
                short bv = f2bf(v);
                s_x1T[o * X1TS + l] = bv;
                pk.s[t] = bv;
            }
            *(short8*)&cat[l * CAS + w * 16]     = pk.v[0];
            *(short8*)&cat[l * CAS + w * 16 + 8] = pk.v[1];
        }
        __syncthreads();   // barrier 1: x1T/cat(x1) visible to all waves

        // ---- MFMA#1: n1^T for i-tile w. A = x1T o-tiles, B = adj cols. ----
        #pragma unroll
        for (int ot = 0; ot < 4; ++ot) {
            f32x4 c = {0.f, 0.f, 0.f, 0.f};
            if (hasKs0) {
                short8 a = *(const short8*)&s_x1T[(16 * ot + l15) * X1TS + 8 * q];
                c = MFMA16(a, adjB0, c);
            }
            if (hasKs1) {
                short8 a = *(const short8*)&s_x1T[(16 * ot + l15) * X1TS + 8 * q + 32];
                c = MFMA16(a, adjB1, c);
            }
            // C: col i = 16w+l15 (lane), rows o = 16ot+4q+reg -> b64 write
            short4v nv;
            nv[0] = f2bf(c[0]); nv[1] = f2bf(c[1]);
            nv[2] = f2bf(c[2]); nv[3] = f2bf(c[3]);
            *(short4v*)&cat[(16 * w + l15) * CAS + 64 + 16 * ot + 4 * q] = nv;
        }
        __syncthreads();   // barrier 2: n1 consumed cross-wave; also fences
                           // s_x1T reuse by next iteration's phase 1

        // ---- MFMA#2: wave w owns o-tile nt=w; loop all 4 i-tiles ----
        {
            f32x4 z = {0.f, 0.f, 0.f, 0.f};
            f32x4 acc2[4] = {z, z, z, z};
            #pragma unroll
            for (int it2 = 0; it2 < 4; ++it2) {
                short8 a2[4];
                #pragma unroll
                for (int ks = 0; ks < 4; ++ks)
                    a2[ks] = *(const short8*)&cat[(16 * it2 + l15) * CAS + 32 * ks + 8 * q];
                #pragma unroll
                for (int ks = 0; ks < 4; ++ks) {
                    acc2[it2] = MFMA16(a2[ks], whf[ks], acc2[it2]);
                    acc2[it2] = MFMA16(a2[ks], wlf[ks], acc2[it2]);
                }
            }
            float total = 0.f;
            #pragma unroll
            for (int it2 = 0; it2 < 4; ++it2) {
                float s = fmaxf(acc2[it2][0] + bo, 0.f) + fmaxf(acc2[it2][1] + bo, 0.f)
                        + fmaxf(acc2[it2][2] + bo, 0.f) + fmaxf(acc2[it2][3] + bo, 0.f);
                s += __shfl_xor(s, 16);
                s += __shfl_xor(s, 32);
                total += s;           // ((s0+s1)+s2)+s3 — same order as before
            }
            if (l < 16)
                feats[(size_t)m * 64 + 16 * w + l15] = total;
        }
        // no trailing barrier: next iter writes cat buffer pb^1; x1T writes are
        // fenced by barrier 2 above (all x1T reads complete before it).
        x0a = nxa; x0b = nxb; m = mn; pb ^= 1;
    }
}

// ---------------------------------------------------------------------------
// GEMM: C[M x 512] = A[M x K] @ BT[K x 512] + bias1 + bias2  (verified)
// ---------------------------------------------------------------------------
template <int K>
__launch_bounds__(256, 2)
__global__ void gemm512_kernel(const float* __restrict__ A, const float* __restrict__ BT,
                               const float* __restrict__ bias1, const float* __restrict__ bias2,
                               float* __restrict__ C) {
    constexpr int K4 = K / 4;
    __shared__ __align__(16) float s_a[64 * K];
    const int tid = threadIdx.x;
    const int m0 = blockIdx.x * 64;
    const int j0 = blockIdx.y * 128;

    const float4* Ag = (const float4*)A;
    for (int e = tid; e < 16 * K; e += 256) {
        int row = e / K4, c = e % K4;
        ((float4*)s_a)[row * K4 + (c ^ ((row >> 2) & 7))] = Ag[(size_t)(m0 + row) * K4 + c];
    }
    __syncthreads();

    const int ti = tid >> 4, tj = tid & 15;
    const int swz = ti & 7;
    const int j = j0 + tj * 8;
    const int jb = (j0 >> 2) + tj * 2;
    const float4* BT4 = (const float4*)BT;

    float4 accL[4], accH[4];
    #pragma unroll
    for (int ii = 0; ii < 4; ++ii) {
        accL[ii] = make_float4(0.f, 0.f, 0.f, 0.f);
        accH[ii] = make_float4(0.f, 0.f, 0.f, 0.f);
    }
    for (int c = 0; c < K4; ++c) {
        float4 a4[4];
        #pragma unroll
        for (int ii = 0; ii < 4; ++ii)
            a4[ii] = ((const float4*)s_a)[(4 * ti + ii) * K4 + (c ^ swz)];
        #pragma unroll
        for (int kk = 0; kk < 4; ++kk) {
            float4 b1 = BT4[(size_t)(c * 4 + kk) * 128 + jb];
            float4 b2 = BT4[(size_t)(c * 4 + kk) * 128 + jb + 1];
            #pragma unroll
            for (int ii = 0; ii < 4; ++ii) {
                float av = f4c(a4[ii], kk);
                fma4(accL[ii], av, b1);
                fma4(accH[ii], av, b2);
            }
        }
    }
    float4 bL = make_float4(bias1[j] + bias2[j], bias1[j + 1] + bias2[j + 1],
                            bias1[j + 2] + bias2[j + 2], bias1[j + 3] + bias2[j + 3]);
    float4 bH = make_float4(bias1[j + 4] + bias2[j + 4], bias1[j + 5] + bias2[j + 5],
                            bias1[j + 6] + bias2[j + 6], bias1[j + 7] + bias2[j + 7]);
    #pragma unroll
    for (int ii = 0; ii < 4; ++ii) {
        size_t row = (size_t)(m0 + 4 * ti + ii);
        float4 oL = make_float4(accL[ii].x + bL.x, accL[ii].y + bL.y,
                                accL[ii].z + bL.z, accL[ii].w + bL.w);
        float4 oH = make_float4(accH[ii].x + bH.x, accH[ii].y + bH.y,
                                accH[ii].z + bH.z, accH[ii].w + bH.w);
        ((float4*)C)[(row * 512 + j) >> 2] = oL;
        ((float4*)C)[(row * 512 + j + 4) >> 2] = oH;
    }
}

// ---------------------------------------------------------------------------
// LSTM recurrence v4: MFMA (unchanged from R14/R15).
// ---------------------------------------------------------------------------
#define HS 136    // s_h row stride in shorts (68 dwords = 4 mod 32)
#define GS 516    // s_g2 row stride in floats (516 = 4 mod 32, 16B-mult)

template <bool FINAL>
__launch_bounds__(512)
__global__ void lstm_mfma(const float* __restrict__ xg, const short* __restrict__ whhfG,
                          float* __restrict__ out0,
                          const float* __restrict__ Wc1, const float* __restrict__ bc1,
                          const float* __restrict__ Wc2, const float* __restrict__ bc2,
                          float* __restrict__ out) {
    __shared__ __align__(16) short s_h[16 * HS];    // h bf16 [m][k]
    __shared__ __align__(16) float s_g2[16 * GS];   // mfma gates fp32 [m][n]
    __shared__ __align__(16) float s_hid[16 * 68];
    const int tid = threadIdx.x;
    const int w = tid >> 6, l = tid & 63, quad = l >> 4, l15 = l & 15;
    const int b0 = blockIdx.x * 16;
    const int u = tid & 127, r0 = tid >> 7;

    short8 whf[16], wlf[16];
    #pragma unroll
    for (int nt = 0; nt < 4; ++nt)
        #pragma unroll
        for (int ks = 0; ks < 4; ++ks) {
            size_t NT = (size_t)(w * 4 + nt);
            whf[nt * 4 + ks] = *(const short8*)(whhfG + (((NT * 4 + ks) * 2 + 0) * 64 + l) * 8);
            wlf[nt * 4 + ks] = *(const short8*)(whhfG + (((NT * 4 + ks) * 2 + 1) * 64 + l) * 8);
        }

    float c[4] = {0.f, 0.f, 0.f, 0.f};
    for (int e = tid; e < 16 * HS; e += 512) s_h[e] = 0;
    __syncthreads();

    for (int t = 0; t < 31; ++t) {
        float xgv[16];
        #pragma unroll
        for (int j = 0; j < 4; ++j) {
            size_t base = ((size_t)(b0 + r0 * 4 + j) * PNUM + t) * 512 + u;
            xgv[j * 4 + 0] = xg[base];
            xgv[j * 4 + 1] = xg[base + 128];
            xgv[j * 4 + 2] = xg[base + 256];
            xgv[j * 4 + 3] = xg[base + 384];
        }

        short8 af[4];
        #pragma unroll
        for (int ks = 0; ks < 4; ++ks)
            af[ks] = *(const short8*)&s_h[l15 * HS + ks * 32 + quad * 8];
        f32x4 z = {0.f, 0.f, 0.f, 0.f};
        f32x4 acc[4] = {z, z, z, z};
        #pragma unroll
        for (int nt = 0; nt < 4; ++nt)
            #pragma unroll
            for (int ks = 0; ks < 4; ++ks) {
                acc[nt] = MFMA16(af[ks], whf[nt * 4 + ks], acc[nt]);
                acc[nt] = MFMA16(af[ks], wlf[nt * 4 + ks], acc[nt]);
            }
        #pragma unroll
        for (int nt = 0; nt < 4; ++nt) {
            int n = w * 64 + nt * 16 + l15;
            #pragma unroll
            for (int reg = 0; reg < 4; ++reg)
                s_g2[(quad * 4 + reg) * GS + n] = acc[nt][reg];
        }
        __syncthreads();

        #pragma unroll
        for (int j = 0; j < 4; ++j) {
            int rr = r0 * 4 + j;
            float gi = xgv[j * 4 + 0] + s_g2[rr * GS + u];
            float gf = xgv[j * 4 + 1] + s_g2[rr * GS + 128 + u];
            float gg = xgv[j * 4 + 2] + s_g2[rr * GS + 256 + u];
            float go = xgv[j * 4 + 3] + s_g2[rr * GS + 384 + u];
            float cn = sigf(gf) * c[j] + sigf(gi) * tanhfast(gg);
            float h = sigf(go) * tanhfast(cn);
            c[j] = cn;
            s_h[rr * HS + u] = f2bf(h);
            if (!FINAL)
                out0[((size_t)(b0 + rr) * PNUM + t) * 128 + u] = h;
        }
        __syncthreads();
    }

    if (FINAL) {
        #pragma unroll
        for (int it2 = 0; it2 < 2; ++it2) {
            int item = tid + it2 * 512;
            int rr = item >> 6, uu = item & 63;
            float acc = bc1[uu];
            const float* wv = Wc1 + (size_t)uu * 128;
            #pragma unroll 8
            for (int k = 0; k < 128; ++k) acc += wv[k] * bf2f(s_h[rr * HS + k]);
            s_hid[rr * 68 + uu] = fmaxf(acc, 0.f);
        }
        __syncthreads();
        if (tid < 176) {
            int rr = tid / 11, cc = tid % 11;
            float acc = bc2[cc];
            #pragma unroll
            for (int uu = 0; uu < 64; ++uu) acc += Wc2[cc * 64 + uu] * s_hid[rr * 68 + uu];
            out[(size_t)(b0 + rr) * 11 + cc] = acc;
        }
    }
}

// ---------------------------------------------------------------------------
extern "C" void kernel_launch(void* const* d_in, const int* in_sizes, int n_in,
                              void* d_out, int out_size, void* d_ws, size_t ws_size,
                              hipStream_t stream) {
    (void)in_sizes; (void)n_in; (void)out_size; (void)ws_size;
    const float* I    = (const float*)d_in[0];
    const float* Q    = (const float*)d_in[1];
    const float* ew   = (const float*)d_in[2];
    const float* Wn1  = (const float*)d_in[3];
    const float* bn1  = (const float*)d_in[4];
    const float* Ws1  = (const float*)d_in[5];
    const float* bs1  = (const float*)d_in[6];
    const float* Wn2  = (const float*)d_in[7];
    const float* bn2  = (const float*)d_in[8];
    const float* Ws2  = (const float*)d_in[9];
    const float* bs2  = (const float*)d_in[10];
    const float* Wih0 = (const float*)d_in[11];
    const float* Whh0 = (const float*)d_in[12];
    const float* bih0 = (const float*)d_in[13];
    const float* bhh0 = (const float*)d_in[14];
    const float* Wih1 = (const float*)d_in[15];
    const float* Whh1 = (const float*)d_in[16];
    const float* bih1 = (const float*)d_in[17];
    const float* bhh1 = (const float*)d_in[18];
    const float* Wc1  = (const float*)d_in[19];
    const float* bc1  = (const float*)d_in[20];
    const float* Wc2  = (const float*)d_in[21];
    const float* bc2  = (const float*)d_in[22];
    float* out = (float*)d_out;

    // workspace (floats): ~90.4 MB
    float* wsp   = (float*)d_ws;
    float* adjn  = wsp;                           // 4096
    float* WihT0 = adjn  + 4096;                  // 32768
    float* WihT1 = WihT0 + 32768;                 // 65536
    short* adjfG  = (short*)(WihT1 + 65536);      // 3072 shorts
    short* wcatfG = adjfG + 3072;                 // 16384 shorts
    short* whhf0G = wcatfG + 16384;               // 131072 shorts
    short* whhf1G = whhf0G + 131072;              // 131072 shorts  (=> 140800 floats total)
    float* feats = WihT1 + 65536 + 140800;        // 2031616
    float* out0  = feats + 2031616;               // 4063232
    float* xg    = out0  + 4063232;               // 16252928 (shared by both layers)

    adj_kernel<<<1, 64, 0, stream>>>(ew, adjn);
    prep_kernel<<<522, 256, 0, stream>>>(Wih0, Whh0, Wih1, Whh1, adjn, Ws2, Wn2,
                                         WihT0, WihT1, adjfG, wcatfG, whhf0G, whhf1G);
    sage_mfma<<<SGRID, 256, 0, stream>>>(I, Q, adjn, Wn1, bn1, Ws1, bs1,
                                         bn2, bs2, adjfG, wcatfG, feats);
    gemm512_kernel<64><<<dim3(496, 4), 256, 0, stream>>>(feats, WihT0, bih0, bhh0, xg);
    lstm_mfma<false><<<64, 512, 0, stream>>>(xg, whhf0G, out0,
                                             nullptr, nullptr, nullptr, nullptr, nullptr);
    gemm512_kernel<128><<<dim3(496, 4), 256, 0, stream>>>(out0, WihT1, bih1, bhh1, xg);
    lstm_mfma<true><<<64, 512, 0, stream>>>(xg, whhf1G, nullptr,
                                            Wc1, bc1, Wc2, bc2, out);
}